// Round 8
// baseline (266.129 us; speedup 1.0000x reference)
//
#include <hip/hip_runtime.h>
#include <math.h>

// Problem constants
#define T_  204
#define I_  5
#define H_  24
#define L_  10
#define O_  612
#define Bsz 8192

typedef _Float16 half8 __attribute__((ext_vector_type(8)));
typedef _Float16 half2t __attribute__((ext_vector_type(2)));
typedef float    float4t __attribute__((ext_vector_type(4)));

union U16B { float4t f4; half8 h8; float f[4]; _Float16 h[8]; half2t h2[4]; };

__device__ __forceinline__ float fast_rcp(float x){ return __builtin_amdgcn_rcpf(x); }
__device__ __forceinline__ float fast_ex2(float x){ return __builtin_amdgcn_exp2f(x); }
__device__ __forceinline__ half2t pk2(float a, float b){
    return __builtin_bit_cast(half2t, __builtin_amdgcn_cvt_pkrtz(a, b));
}

#define MFMA16(a,b,c) __builtin_amdgcn_mfma_f32_16x16x32_f16((a),(b),(c),0,0,0)

#define L2E  1.44269504f
#define L2E2 2.88539008f

// Unit owned by lane-quad q, tile T (q<3: 8q+T; q==3: overflow units 6,7,14,15,22,23)
__device__ __forceinline__ int unit_of(int q, int T) {
    return (q < 3) ? (8*q + T) : (8*(T >> 1) + 6 + (T & 1));
}

// Prepack fc0_w into per-timestep fp16 A-fragments (A[m=l][k=j], zeros elsewhere).
__global__ __launch_bounds__(64)
void pack_fc0(const float* __restrict__ fc0_w, float4t* __restrict__ dst)
{
    const int t = blockIdx.x, lane = threadIdx.x;
    const int m = lane & 15, q = lane >> 4;
    U16B v;
    #pragma unroll
    for (int i = 0; i < 8; ++i) {
        const int k = 8*q + i;
        float f = (m < L_ && k < H_) ? fc0_w[m*(T_*H_) + t*H_ + k] : 0.0f;
        v.h[i] = (_Float16)f;
    }
    dst[t*64 + lane] = v.f4;
}

// R19: cross-round fit: wall ~= 290cy x ACT-BLOCK count (R11 6->1740, R14
// 8->2320, R12 12->3560, R15 6->1680 despite -30% trans). 290 = ~140 issue +
// ~150 exposed trans/rcp chain latency per block => LLVM clusters each unit's
// act chain back-to-back (reg-pressure heuristic); 6 independent chains never
// overlap. A 2nd HW wave fills exactly these bubbles (R16: 1.44x per-SIMD).
// Fix: pin breadth-first phases with sched_barrier(0): {24 exps} | {6 denom+
// rcp} | {6 c+exp} | {6 rcp+h}. Within a phase 6 chains hide each other.
// Math identical to R15/R18 (absmax 0.001953125). Ring prefetch kept (R18).
#define POS(K, faK, xsK)                                                        \
  {                                                                             \
    float4t D0 = MFMA16(Ag[0], B.h8, zf4);                                      \
    float4t D1 = MFMA16(Ag[1], B.h8, zf4);                                      \
    float4t D2 = MFMA16(Ag[2], B.h8, zf4);                                      \
    float4t D3 = MFMA16(Ag[3], B.h8, zf4);                                      \
    float4t D4 = MFMA16(Ag[4], B.h8, zf4);                                      \
    float4t D5 = MFMA16(Ag[5], B.h8, zf4);                                      \
    float4t Dv[6] = {D0, D1, D2, D3, D4, D5};                                   \
    float hh[6];                                                                \
    float ei[6], ef[6], eg[6], eo[6];                                           \
    _Pragma("unroll")                                                           \
    for (int u = 0; u < 6; ++u) {                                               \
      ei[u] = fast_ex2(Dv[u][0] * -L2E);                                        \
      ef[u] = fast_ex2(Dv[u][1] * -L2E);                                        \
      eg[u] = fast_ex2(Dv[u][2] *  L2E2);                                       \
      eo[u] = fast_ex2(Dv[u][3] * -L2E);                                        \
    }                                                                           \
    __builtin_amdgcn_sched_barrier(0);                                          \
    float R1[6], nm[6];                                                         \
    _Pragma("unroll")                                                           \
    for (int u = 0; u < 6; ++u) {                                               \
      const float Dn1 = 1.f + ef[u];                                            \
      const float P   = (1.f + ei[u]) * (eg[u] + 1.f);                          \
      R1[u] = fast_rcp(Dn1 * P);                                                \
      nm[u] = fmaf(c_[u], P, Dn1 * (eg[u] - 1.f));                              \
    }                                                                           \
    __builtin_amdgcn_sched_barrier(0);                                          \
    float es[6];                                                                \
    _Pragma("unroll")                                                           \
    for (int u = 0; u < 6; ++u) {                                               \
      c_[u] = nm[u] * R1[u];                                                    \
      es[u] = fast_ex2(__builtin_fabsf(c_[u]) * -L2E2);                         \
    }                                                                           \
    __builtin_amdgcn_sched_barrier(0);                                          \
    _Pragma("unroll")                                                           \
    for (int u = 0; u < 6; ++u) {                                               \
      const float R2 = fast_rcp((1.f + eo[u]) * (1.f + es[u]));                 \
      hh[u] = __builtin_copysignf((1.f - es[u]) * R2, c_[u]);                   \
    }                                                                           \
    const float P0 = __builtin_bit_cast(float, pk2(hh[0], hh[1]));              \
    const float P1 = __builtin_bit_cast(float, pk2(hh[2], hh[3]));              \
    const float P2 = __builtin_bit_cast(float, pk2(hh[4], hh[5]));              \
    const float r0 = __shfl(P0, src, 64);                                       \
    const float r1 = __shfl(P1, src, 64);                                       \
    const float r2 = __shfl(P2, src, 64);                                       \
    const float rcv = (q == 0) ? r0 : ((q == 1) ? r1 : r2);                     \
    if (q < 3) {                                                                \
      B.h2[0] = __builtin_bit_cast(half2t, P0);                                 \
      B.h2[1] = __builtin_bit_cast(half2t, P1);                                 \
      B.h2[2] = __builtin_bit_cast(half2t, P2);                                 \
      B.h2[3] = __builtin_bit_cast(half2t, rcv);                                \
    } else {                                                                    \
      B.h2[0] = pk2(xsK[0], xsK[1]);                                            \
      B.h2[1] = pk2(xsK[2], xsK[3]);                                            \
      B.h2[2] = pk2(xsK[4], 1.0f);                                              \
      B.h2[3] = pk2(0.f, 0.f);                                                  \
    }                                                                           \
    { U16B fF; fF.f4 = faK;                                                     \
      accF = MFMA16(fF.h8, B.h8, accF); }                                       \
    /* slot reloads: consumed again at step t+K+4 (4-step vmcnt shadow) */      \
    { const int tf = (t + K + 4 < T_) ? t + K + 4 : T_ - 1;                     \
      faK = fc0A[tf*64 + lane]; }                                               \
    if (q == 3) {                                                               \
      const int txi = (t + K + 5 < T_) ? t + K + 5 : T_ - 1;                    \
      const float* xq = xp + txi*I_;                                            \
      _Pragma("unroll")                                                         \
      for (int i = 0; i < I_; ++i) xsK[i] = xq[i];                              \
    }                                                                           \
  }

__global__ __launch_bounds__(64)
void lstm_mfma(const float* __restrict__ x,
               const float* __restrict__ W_ih,
               const float* __restrict__ W_hh,
               const float* __restrict__ b_ih,
               const float* __restrict__ b_hh,
               const float* __restrict__ fc0_b,
               const float* __restrict__ out_w,
               const float* __restrict__ out_b,
               const float4t* __restrict__ fc0A,   // prepacked in d_ws
               float* __restrict__ out)
{
    __shared__ __align__(16) _Float16 actL[16*24];  // epilogue staging only

    const int lane = threadIdx.x;
    const int m = lane & 15;        // element col / A row-within-tile
    const int q = lane >> 4;        // quad
    const int elem = blockIdx.x * 16 + m;
    const int src = 48 + m;         // bpermute source lane (q3 overflow pairs)

    const float4t zf4 = {0.f, 0.f, 0.f, 0.f};

    // ---- gate A-fragments ----
    half8 Ag[6];
    #pragma unroll
    for (int T6 = 0; T6 < 6; ++T6) {
        const int u = unit_of(m >> 2, T6);
        const int srow = (m & 3) * H_ + u;       // torch gate-major row
        float wv[8];
        if (q < 3) {
            const float4t* pw = (const float4t*)(W_hh + srow*H_ + 8*q);
            float4t wa = pw[0], wb = pw[1];
            #pragma unroll
            for (int i = 0; i < 4; ++i) { wv[i] = wa[i]; wv[4+i] = wb[i]; }
        } else {
            #pragma unroll
            for (int i = 0; i < 8; ++i) wv[i] = 0.f;
            #pragma unroll
            for (int i = 0; i < I_; ++i) wv[i] = W_ih[srow*I_ + i];
            wv[5] = b_ih[srow] + b_hh[srow];
        }
        U16B tw;
        #pragma unroll
        for (int i = 0; i < 8; ++i) tw.h[i] = (_Float16)wv[i];
        Ag[T6] = tw.h8;
    }

    const float* xp = x + (size_t)elem * (T_*I_);

    // ---- initial B-frag [h=0 | x_0 | 1 | 0,0] ----
    U16B B;
    if (q == 3) {
        B.h2[0] = pk2(xp[0], xp[1]);
        B.h2[1] = pk2(xp[2], xp[3]);
        B.h2[2] = pk2(xp[4], 1.0f);
        B.h2[3] = pk2(0.f, 0.f);
    } else {
        B.f4 = zf4;
    }

    // ---- depth-4 prefetch ring, named slots (slot k: data for step t0+k) ----
    float4t fa0 = fc0A[0*64 + lane];
    float4t fa1 = fc0A[1*64 + lane];
    float4t fa2 = fc0A[2*64 + lane];
    float4t fa3 = fc0A[3*64 + lane];
    float xs0[I_] = {0,0,0,0,0}, xs1[I_] = {0,0,0,0,0};
    float xs2[I_] = {0,0,0,0,0}, xs3[I_] = {0,0,0,0,0};
    if (q == 3) {
        #pragma unroll
        for (int i = 0; i < I_; ++i) {
            xs0[i] = xp[1*I_ + i];   // x(1) consumed at t=0
            xs1[i] = xp[2*I_ + i];
            xs2[i] = xp[3*I_ + i];
            xs3[i] = xp[4*I_ + i];
        }
    }

    float c_[6] = {0,0,0,0,0,0};
    float4t accF = zf4;

    // ================= time loop: 51 x 4 steps, copy-free ring =============
    #pragma unroll 1
    for (int t = 0; t < T_; t += 4) {
        POS(0, fa0, xs0)
        POS(1, fa1, xs1)
        POS(2, fa2, xs2)
        POS(3, fa3, xs3)
    }

    // ================= epilogue (validated R7/R8) =================
    float av[4];
    #pragma unroll
    for (int r = 0; r < 4; ++r) {
        const int l = 4*q + r;
        const float fb = (l < L_) ? fc0_b[l] : 0.f;
        const float v = accF[r] + fb;
        av[r] = (l < L_) ? fmaxf(v, 0.f) : 0.f;
    }
    *(half2t*)(&actL[m*24 + 4*q])     = pk2(av[0], av[1]);
    *(half2t*)(&actL[m*24 + 4*q + 2]) = pk2(av[2], av[3]);
    __builtin_amdgcn_wave_barrier();

    U16B Ba;
    if (q < 2) Ba.f4 = *(const float4t*)(&actL[m*24 + q*8]);
    else       Ba.f4 = zf4;            // k>=16 unused (out_w A-frag zero there)

    for (int Tt = 0; Tt < 39; ++Tt) {
        const int row = 16*Tt + m;
        float w0=0.f,w1=0.f,w2=0.f,w3=0.f,w4=0.f,w5=0.f,w6=0.f,w7=0.f;
        if (row < O_ && q < 2) {
            const float2* p2 = (const float2*)(out_w + row*L_);
            if (q == 0) {
                float2 a = p2[0], b = p2[1], cc = p2[2], dd = p2[3];
                w0=a.x; w1=a.y; w2=b.x; w3=b.y; w4=cc.x; w5=cc.y; w6=dd.x; w7=dd.y;
            } else {
                float2 a = p2[4];
                w0=a.x; w1=a.y;
            }
        }
        U16B Aw;
        Aw.h2[0] = pk2(w0,w1); Aw.h2[1] = pk2(w2,w3);
        Aw.h2[2] = pk2(w4,w5); Aw.h2[3] = pk2(w6,w7);

        float4t dd = MFMA16(Aw.h8, Ba.h8, zf4);

        const int ob = 16*Tt + 4*q;
        if (ob < O_) {
            const float4t bias = *(const float4t*)(out_b + ob);
            #pragma unroll
            for (int r = 0; r < 4; ++r) dd[r] += bias[r];
            *(float4t*)(out + (size_t)elem*O_ + ob) = dd;
        }
    }
}

extern "C" void kernel_launch(void* const* d_in, const int* in_sizes, int n_in,
                              void* d_out, int out_size, void* d_ws, size_t ws_size,
                              hipStream_t stream)
{
    const float* x     = (const float*)d_in[0];
    const float* W_ih  = (const float*)d_in[1];
    const float* W_hh  = (const float*)d_in[2];
    const float* b_ih  = (const float*)d_in[3];
    const float* b_hh  = (const float*)d_in[4];
    const float* fc0_w = (const float*)d_in[5];
    const float* fc0_b = (const float*)d_in[6];
    const float* out_w = (const float*)d_in[7];
    const float* out_b = (const float*)d_in[8];
    float* out = (float*)d_out;
    (void)ws_size;

    pack_fc0<<<dim3(T_), dim3(64), 0, stream>>>(fc0_w, (float4t*)d_ws);
    lstm_mfma<<<dim3(Bsz/16), dim3(64), 0, stream>>>(
        x, W_ih, W_hh, b_ih, b_hh, fc0_b, out_w, out_b,
        (const float4t*)d_ws, out);
}

// Round 9
// 195.246 us; speedup vs baseline: 1.3630x; 1.3630x over previous
//
#include <hip/hip_runtime.h>
#include <math.h>

// Problem constants
#define T_  204
#define I_  5
#define H_  24
#define L_  10
#define O_  612
#define Bsz 8192

typedef _Float16 half8 __attribute__((ext_vector_type(8)));
typedef _Float16 half2t __attribute__((ext_vector_type(2)));
typedef float    float4t __attribute__((ext_vector_type(4)));

union U16B { float4t f4; half8 h8; float f[4]; _Float16 h[8]; half2t h2[4]; };

__device__ __forceinline__ float fast_rcp(float x){ return __builtin_amdgcn_rcpf(x); }
__device__ __forceinline__ float fast_ex2(float x){ return __builtin_amdgcn_exp2f(x); }
__device__ __forceinline__ half2t pk2(float a, float b){
    return __builtin_bit_cast(half2t, __builtin_amdgcn_cvt_pkrtz(a, b));
}

#define MFMA16(a,b,c) __builtin_amdgcn_mfma_f32_16x16x32_f16((a),(b),(c),0,0,0)

#define L2E  1.44269504f
#define L2E2 2.88539008f

// Unit owned by lane-quad q, tile T (q<3: 8q+T; q==3: overflow units 6,7,14,15,22,23)
__device__ __forceinline__ int unit_of(int q, int T) {
    return (q < 3) ? (8*q + T) : (8*(T >> 1) + 6 + (T & 1));
}

// Prepack fc0_w into per-timestep fp16 A-fragments (A[m=l][k=j], zeros elsewhere).
__global__ __launch_bounds__(64)
void pack_fc0(const float* __restrict__ fc0_w, float4t* __restrict__ dst)
{
    const int t = blockIdx.x, lane = threadIdx.x;
    const int m = lane & 15, q = lane >> 4;
    U16B v;
    #pragma unroll
    for (int i = 0; i < 8; ++i) {
        const int k = 8*q + i;
        float f = (m < L_ && k < H_) ? fc0_w[m*(T_*H_) + t*H_ + k] : 0.0f;
        v.h[i] = (_Float16)f;
    }
    dst[t*64 + lane] = v.f4;
}

// R15 fused-denominator activation, per unit (bitwise-identical results)
#define ACT1(Dv, cc, hh)                                                        \
  {                                                                             \
    const float ei = fast_ex2((Dv)[0] * -L2E);                                  \
    const float ef = fast_ex2((Dv)[1] * -L2E);                                  \
    const float eg = fast_ex2((Dv)[2] *  L2E2);                                 \
    const float eo = fast_ex2((Dv)[3] * -L2E);                                  \
    const float Dn1 = 1.f + ef;                                                 \
    const float Dn2 = 1.f + ei;                                                 \
    const float Dn3 = eg + 1.f;                                                 \
    const float G   = eg - 1.f;                                                 \
    const float P   = Dn2 * Dn3;                                                \
    const float R1  = fast_rcp(Dn1 * P);                                        \
    const float nm  = fmaf((cc), P, Dn1 * G);                                   \
    (cc) = nm * R1;                                                             \
    const float es  = fast_ex2(__builtin_fabsf(cc) * -L2E2);                    \
    const float R2  = fast_rcp((1.f + eo) * (1.f + es));                        \
    (hh) = __builtin_copysignf((1.f - es) * R2, (cc));                          \
  }

// R20: R18's residual = per-SIMD issue 920cy + 670cy stall at 1 wave/SIMD on
// only 512 of 1024 SIMDs (512 batch-16 waves max). R16 proved a sibling HW
// wave fills the stall; R19 proved the compiler already fills what one wave
// can. Fix: batch-8 per wave, 1024 waves -> ~1 wave on ALL 1024 SIMDs, and
// per-wave act work HALVED. Trick: B cols 8-15 DUPLICATE cols 0-7, so lane
// (q,m>=8) natively gets the same gate D as (q,m-8): act splits cleanly
// (m<8: tiles 0-2, m>=8: tiles 3-5; 3 ACT blocks/lane, 21 trans vs 42), no
// D redistribution (register select). h-exchange = 6 parallel depth-1 shfls.
// Each (batch,unit) cell computed exactly once; identical f32 math + pk2
// roundings -> bitwise-identical output. Ring prefetch kept (R18).
#define POS(K, faK, xsK)                                                        \
  {                                                                             \
    float4t D0 = MFMA16(Ag[0], B.h8, zf4);                                      \
    float4t D1 = MFMA16(Ag[1], B.h8, zf4);                                      \
    float4t D2 = MFMA16(Ag[2], B.h8, zf4);                                      \
    float4t D3 = MFMA16(Ag[3], B.h8, zf4);                                      \
    float4t D4 = MFMA16(Ag[4], B.h8, zf4);                                      \
    float4t D5 = MFMA16(Ag[5], B.h8, zf4);                                      \
    const float4t E0 = mhi ? D3 : D0;                                           \
    const float4t E1 = mhi ? D4 : D1;                                           \
    const float4t E2 = mhi ? D5 : D2;                                           \
    float h0, h1, h2;                                                           \
    ACT1(E0, c0, h0)                                                            \
    ACT1(E1, c1, h1)                                                            \
    ACT1(E2, c2, h2)                                                            \
    /* partner (lane^8) exchange + q3 overflow pulls: all depth-1, parallel */  \
    const float s0 = __shfl(h0, sPart, 64);                                     \
    const float s1 = __shfl(h1, sPart, 64);                                     \
    const float s2 = __shfl(h2, sPart, 64);                                     \
    const float rA = __shfl(h0, srcA, 64);                                      \
    const float rB = __shfl(h1, srcB, 64);                                      \
    const float rC = __shfl(h2, srcC, 64);                                      \
    if (q < 3) {                                                                \
      /* lo lane: own h = units 8q+0..2, partner s = 8q+3..5 (hi: swapped) */   \
      B.h2[0] = pk2(mhi ? s0 : h0, mhi ? s1 : h1);                              \
      B.h2[1] = pk2(mhi ? s2 : h2, mhi ? h0 : s0);                              \
      B.h2[2] = pk2(mhi ? h1 : s1, mhi ? h2 : s2);                              \
      /* (8q+6,8q+7): q0=(u6,u7)=(rA,rB)@48+mb; q1=(u14,u15)=(rC@48,rA@56);  */ \
      /* q2=(u22,u23)=(rB,rC)@56+mb  (srcs baked into srcA/B/C)              */ \
      const float pa = (q == 0) ? rA : ((q == 1) ? rC : rB);                    \
      const float pb = (q == 0) ? rB : ((q == 1) ? rA : rC);                    \
      B.h2[3] = pk2(pa, pb);                                                    \
    } else {                                                                    \
      B.h2[0] = pk2(xsK[0], xsK[1]);                                            \
      B.h2[1] = pk2(xsK[2], xsK[3]);                                            \
      B.h2[2] = pk2(xsK[4], 1.0f);                                              \
      B.h2[3] = pk2(0.f, 0.f);                                                  \
    }                                                                           \
    { U16B fF; fF.f4 = faK;                                                     \
      accF = MFMA16(fF.h8, B.h8, accF); }                                       \
    /* slot reloads: consumed again at step t+K+4 (4-step vmcnt shadow) */      \
    { const int tf = (t + K + 4 < T_) ? t + K + 4 : T_ - 1;                     \
      faK = fc0A[tf*64 + lane]; }                                               \
    if (q == 3) {                                                               \
      const int txi = (t + K + 5 < T_) ? t + K + 5 : T_ - 1;                    \
      const float* xq = xp + txi*I_;                                            \
      _Pragma("unroll")                                                         \
      for (int i = 0; i < I_; ++i) xsK[i] = xq[i];                              \
    }                                                                           \
  }

__global__ __launch_bounds__(64)
void lstm_mfma(const float* __restrict__ x,
               const float* __restrict__ W_ih,
               const float* __restrict__ W_hh,
               const float* __restrict__ b_ih,
               const float* __restrict__ b_hh,
               const float* __restrict__ fc0_b,
               const float* __restrict__ out_w,
               const float* __restrict__ out_b,
               const float4t* __restrict__ fc0A,   // prepacked in d_ws
               float* __restrict__ out)
{
    __shared__ __align__(16) _Float16 actL[16*24];  // epilogue staging only

    const int lane = threadIdx.x;
    const int m = lane & 15;         // B col (batch, cols 8-15 duplicate 0-7)
    const int q = lane >> 4;         // quad
    const int mb = m & 7;            // batch sub-index
    const bool mhi = (m >= 8);       // upper half: owns unit tiles 3-5
    const int eb = blockIdx.x * 8 + mb;   // batch element (valid, all lanes)

    // shuffle source lanes (per-lane constants)
    const int sPart = lane ^ 8;                     // partner, same q
    const int srcA = ((q == 1) ? 56 : 48) + mb;     // h0 pull: q0->u6, q1->u15
    const int srcB = ((q == 2) ? 56 : 48) + mb;     // h1 pull: q0->u7, q2->u22
    const int srcC = ((q == 2) ? 56 : 48) + mb;     // h2 pull: q1->u14, q2->u23

    const float4t zf4 = {0.f, 0.f, 0.f, 0.f};

    // ---- gate A-fragments (identical to R18) ----
    half8 Ag[6];
    #pragma unroll
    for (int T6 = 0; T6 < 6; ++T6) {
        const int u = unit_of(m >> 2, T6);
        const int srow = (m & 3) * H_ + u;       // torch gate-major row
        float wv[8];
        if (q < 3) {
            const float4t* pw = (const float4t*)(W_hh + srow*H_ + 8*q);
            float4t wa = pw[0], wb = pw[1];
            #pragma unroll
            for (int i = 0; i < 4; ++i) { wv[i] = wa[i]; wv[4+i] = wb[i]; }
        } else {
            #pragma unroll
            for (int i = 0; i < 8; ++i) wv[i] = 0.f;
            #pragma unroll
            for (int i = 0; i < I_; ++i) wv[i] = W_ih[srow*I_ + i];
            wv[5] = b_ih[srow] + b_hh[srow];
        }
        U16B tw;
        #pragma unroll
        for (int i = 0; i < 8; ++i) tw.h[i] = (_Float16)wv[i];
        Ag[T6] = tw.h8;
    }

    const float* xp = x + (size_t)eb * (T_*I_);

    // ---- initial B-frag [h=0 | x_0 | 1 | 0,0] (q3: all m, duplicated) ----
    U16B B;
    if (q == 3) {
        B.h2[0] = pk2(xp[0], xp[1]);
        B.h2[1] = pk2(xp[2], xp[3]);
        B.h2[2] = pk2(xp[4], 1.0f);
        B.h2[3] = pk2(0.f, 0.f);
    } else {
        B.f4 = zf4;
    }

    // ---- depth-4 prefetch ring, named slots ----
    float4t fa0 = fc0A[0*64 + lane];
    float4t fa1 = fc0A[1*64 + lane];
    float4t fa2 = fc0A[2*64 + lane];
    float4t fa3 = fc0A[3*64 + lane];
    float xs0[I_] = {0,0,0,0,0}, xs1[I_] = {0,0,0,0,0};
    float xs2[I_] = {0,0,0,0,0}, xs3[I_] = {0,0,0,0,0};
    if (q == 3) {
        #pragma unroll
        for (int i = 0; i < I_; ++i) {
            xs0[i] = xp[1*I_ + i];   // x(1) consumed at t=0
            xs1[i] = xp[2*I_ + i];
            xs2[i] = xp[3*I_ + i];
            xs3[i] = xp[4*I_ + i];
        }
    }

    // 3 cell states per lane: units unit_of(q, (mhi?3:0)+j), batch mb
    float c0 = 0.f, c1 = 0.f, c2 = 0.f;
    float4t accF = zf4;

    // ================= time loop: 51 x 4 steps, copy-free ring =============
    #pragma unroll 1
    for (int t = 0; t < T_; t += 4) {
        POS(0, fa0, xs0)
        POS(1, fa1, xs1)
        POS(2, fa2, xs2)
        POS(3, fa3, xs3)
    }

    // ================= epilogue (R7/R8 structure; stores m<8 only) =========
    float av[4];
    #pragma unroll
    for (int r = 0; r < 4; ++r) {
        const int l = 4*q + r;
        const float fb = (l < L_) ? fc0_b[l] : 0.f;
        const float v = accF[r] + fb;
        av[r] = (l < L_) ? fmaxf(v, 0.f) : 0.f;
    }
    *(half2t*)(&actL[m*24 + 4*q])     = pk2(av[0], av[1]);
    *(half2t*)(&actL[m*24 + 4*q + 2]) = pk2(av[2], av[3]);
    __builtin_amdgcn_wave_barrier();

    U16B Ba;
    if (q < 2) Ba.f4 = *(const float4t*)(&actL[m*24 + q*8]);
    else       Ba.f4 = zf4;            // k>=16 unused (out_w A-frag zero there)

    for (int Tt = 0; Tt < 39; ++Tt) {
        const int row = 16*Tt + m;
        float w0=0.f,w1=0.f,w2=0.f,w3=0.f,w4=0.f,w5=0.f,w6=0.f,w7=0.f;
        if (row < O_ && q < 2) {
            const float2* p2 = (const float2*)(out_w + row*L_);
            if (q == 0) {
                float2 a = p2[0], b = p2[1], cc = p2[2], dd = p2[3];
                w0=a.x; w1=a.y; w2=b.x; w3=b.y; w4=cc.x; w5=cc.y; w6=dd.x; w7=dd.y;
            } else {
                float2 a = p2[4];
                w0=a.x; w1=a.y;
            }
        }
        U16B Aw;
        Aw.h2[0] = pk2(w0,w1); Aw.h2[1] = pk2(w2,w3);
        Aw.h2[2] = pk2(w4,w5); Aw.h2[3] = pk2(w6,w7);

        float4t dd = MFMA16(Aw.h8, Ba.h8, zf4);

        const int ob = 16*Tt + 4*q;
        if (ob < O_ && m < 8) {
            const float4t bias = *(const float4t*)(out_b + ob);
            #pragma unroll
            for (int r = 0; r < 4; ++r) dd[r] += bias[r];
            *(float4t*)(out + (size_t)eb*O_ + ob) = dd;
        }
    }
}

extern "C" void kernel_launch(void* const* d_in, const int* in_sizes, int n_in,
                              void* d_out, int out_size, void* d_ws, size_t ws_size,
                              hipStream_t stream)
{
    const float* x     = (const float*)d_in[0];
    const float* W_ih  = (const float*)d_in[1];
    const float* W_hh  = (const float*)d_in[2];
    const float* b_ih  = (const float*)d_in[3];
    const float* b_hh  = (const float*)d_in[4];
    const float* fc0_w = (const float*)d_in[5];
    const float* fc0_b = (const float*)d_in[6];
    const float* out_w = (const float*)d_in[7];
    const float* out_b = (const float*)d_in[8];
    float* out = (float*)d_out;
    (void)ws_size;

    pack_fc0<<<dim3(T_), dim3(64), 0, stream>>>(fc0_w, (float4t*)d_ws);
    lstm_mfma<<<dim3(Bsz/8), dim3(64), 0, stream>>>(
        x, W_ih, W_hh, b_ih, b_hh, fc0_b, out_w, out_b,
        (const float4t*)d_ws, out);
}